// Round 13
// baseline (47.990 us; speedup 1.0000x reference)
//
#include <hip/hip_runtime.h>
#include <math.h>

#define NJ  16
#define BLK 256

// DPP quad_perm: cross-lane move WITHIN each 4-lane quad, executed on the
// VALU pipe (v_mov_b32_dpp) — zero DS ops, unlike __shfl (ds_bpermute).
// ctrl = p0 | p1<<2 | p2<<4 | p3<<6 : out-lane k reads in-lane p_k of quad.
template<int CTRL>
__device__ __forceinline__ float qperm(float x) {
    return __int_as_float(__builtin_amdgcn_update_dpp(
        __float_as_int(x), __float_as_int(x), CTRL, 0xF, 0xF, false));
}
#define QP_SHL1 144  // [0,0,1,2]: lane k <- k-1 (k>=1)
#define QP_SHL2 68   // [0,1,0,1]: lane k <- k-2 (k>=2)
#define QP_BCL3 255  // [3,3,3,3]: all lanes <- lane 3 of quad

// Affine 3x4: m[0..8] = row-major R, m[9..11] = p.
struct Mat { float m[12]; };

// C = A @ B (apply B then A): matches T_new = T_old @ A_j as mul(earlier, later).
__device__ __forceinline__ Mat mul(const Mat& A, const Mat& B) {
    Mat C;
    #pragma unroll
    for (int r = 0; r < 3; ++r) {
        float a0 = A.m[3*r+0], a1 = A.m[3*r+1], a2 = A.m[3*r+2];
        C.m[3*r+0] = a0*B.m[0] + a1*B.m[3] + a2*B.m[6];
        C.m[3*r+1] = a0*B.m[1] + a1*B.m[4] + a2*B.m[7];
        C.m[3*r+2] = a0*B.m[2] + a1*B.m[5] + a2*B.m[8];
        C.m[9+r]   = a0*B.m[9] + a1*B.m[10] + a2*B.m[11] + A.m[9+r];
    }
    return C;
}

// srodrigues for one joint: tw6 = (w0..w2, v0..v2), angle qj.
__device__ __forceinline__ Mat buildA(const float* tw6, float qj) {
    float w0 = tw6[0], w1 = tw6[1], w2 = tw6[2];
    float v0 = tw6[3], v1 = tw6[4], v2 = tw6[5];
    float theta = sqrtf(w0*w0 + w1*w1 + w2*w2) + 1e-12f;
    float inv   = __builtin_amdgcn_rcpf(theta);
    float wn0 = w0*inv, wn1 = w1*inv, wn2 = w2*inv;
    float vn0 = v0*inv, vn1 = v1*inv, vn2 = v2*inv;
    float qt  = qj * theta;
    float s   = __sinf(qt);
    float cth = __cosf(qt);
    float c   = 1.0f - cth;
    float ts  = qt - s;
    Mat A;
    A.m[0] = cth + c*wn0*wn0;   A.m[1] = c*wn0*wn1 - s*wn2; A.m[2] = c*wn0*wn2 + s*wn1;
    A.m[3] = c*wn1*wn0 + s*wn2; A.m[4] = cth + c*wn1*wn1;   A.m[5] = c*wn1*wn2 - s*wn0;
    A.m[6] = c*wn2*wn0 - s*wn1; A.m[7] = c*wn2*wn1 + s*wn0; A.m[8] = cth + c*wn2*wn2;
    float cx0 = wn1*vn2 - wn2*vn1;
    float cx1 = wn2*vn0 - wn0*vn2;
    float cx2 = wn0*vn1 - wn1*vn0;
    float d   = wn0*vn0 + wn1*vn1 + wn2*vn2;
    float td  = ts * d;
    A.m[9]  = s*vn0 + c*cx0 + td*wn0;
    A.m[10] = s*vn1 + c*cx1 + td*wn1;
    A.m[11] = s*vn2 + c*cx2 + td*wn2;
    return A;
}

// tw_local for one joint given entry pose, stored immediately.
__device__ __forceinline__ void tw_local_store(
    const Mat& pose, const float* t6, float* twb)
{
    float w0 = t6[0], w1 = t6[1], w2 = t6[2];
    float v0 = t6[3], v1 = t6[4], v2 = t6[5];
    float p0 = pose.m[9], p1 = pose.m[10], p2 = pose.m[11];
    float u0 = v0 - (p1*w2 - p2*w1);
    float u1 = v1 - (p2*w0 - p0*w2);
    float u2 = v2 - (p0*w1 - p1*w0);
    float wl0 = pose.m[0]*w0 + pose.m[3]*w1 + pose.m[6]*w2;
    float wl1 = pose.m[1]*w0 + pose.m[4]*w1 + pose.m[7]*w2;
    float wl2 = pose.m[2]*w0 + pose.m[5]*w1 + pose.m[8]*w2;
    float vl0 = pose.m[0]*u0 + pose.m[3]*u1 + pose.m[6]*u2;
    float vl1 = pose.m[1]*u0 + pose.m[4]*u1 + pose.m[7]*u2;
    float vl2 = pose.m[2]*u0 + pose.m[5]*u1 + pose.m[8]*u2;
    *reinterpret_cast<float4*>(twb)     = make_float4(wl0, wl1, wl2, vl0);
    *reinterpret_cast<float2*>(twb + 4) = make_float2(vl1, vl2);
}

// 4 lanes per element; DPP quad scan; phase-1 partial products saved so
// phase 2 needs NO buildA rebuilds (4 independent tw_local blocks).
__global__ __launch_bounds__(BLK) void poe_fwd(
    const float* __restrict__ q,        // B x 16
    const float* __restrict__ twist,    // 16 x 6 (uniform)
    const float* __restrict__ init_p,   // 3
    const float* __restrict__ init_rpy, // 3
    float* __restrict__ outT,           // B x 16
    float* __restrict__ outTw,          // B x 96
    int nb)
{
    const int g = blockIdx.x * BLK + threadIdx.x;   // global lane
    const int e = g >> 2;                           // batch element
    const int s = g & 3;                            // segment (joints 4s..4s+3)
    if (e >= nb) return;

    float qk[4];
    {
        float4 t = reinterpret_cast<const float4*>(q)[(size_t)e * 4 + s];
        qk[0] = t.x; qk[1] = t.y; qk[2] = t.z; qk[3] = t.w;
    }

    // twist rows 4s..4s+3 (24 floats, L1-resident).
    float tws[24];
    {
        const float4* t4 = reinterpret_cast<const float4*>(twist) + s * 6;
        #pragma unroll
        for (int i = 0; i < 6; ++i) {
            float4 t = t4[i];
            tws[4*i+0] = t.x; tws[4*i+1] = t.y; tws[4*i+2] = t.z; tws[4*i+3] = t.w;
        }
    }

    // ---- phase 1: serial product, KEEPING the partial products ----
    Mat P0 = buildA(&tws[0],  qk[0]);               // A0
    Mat P1 = mul(P0, buildA(&tws[6],  qk[1]));      // A0*A1
    Mat P2 = mul(P1, buildA(&tws[12], qk[2]));      // A0*A1*A2
    Mat P  = mul(P2, buildA(&tws[18], qk[3]));      // full segment product

    // ---- inclusive scan over the quad via DPP (steps 1, 2) ----
    {
        Mat T;
        #pragma unroll
        for (int i = 0; i < 12; ++i) T.m[i] = qperm<QP_SHL1>(P.m[i]);
        Mat M = mul(T, P);
        #pragma unroll
        for (int i = 0; i < 12; ++i) P.m[i] = (s >= 1) ? M.m[i] : P.m[i];
    }
    {
        Mat T;
        #pragma unroll
        for (int i = 0; i < 12; ++i) T.m[i] = qperm<QP_SHL2>(P.m[i]);
        Mat M = mul(T, P);
        #pragma unroll
        for (int i = 0; i < 12; ++i) P.m[i] = (s >= 2) ? M.m[i] : P.m[i];
    }

    // ---- exclusive prefix = entry pose for my segment ----
    Mat entry;
    {
        #pragma unroll
        for (int i = 0; i < 12; ++i) entry.m[i] = qperm<QP_SHL1>(P.m[i]);
        const float id[12] = {1,0,0, 0,1,0, 0,0,1, 0,0,0};
        #pragma unroll
        for (int i = 0; i < 12; ++i) entry.m[i] = (s == 0) ? id[i] : entry.m[i];
    }

    // ---- phase 2: 4 INDEPENDENT tw_local blocks (no rebuilds) ----
    float* twb = outTw + (size_t)g * 24;
    tw_local_store(entry,           &tws[0],  twb + 0);
    {
        Mat ps1 = mul(entry, P0);
        tw_local_store(ps1,         &tws[6],  twb + 6);
    }
    {
        Mat ps2 = mul(entry, P1);
        tw_local_store(ps2,         &tws[12], twb + 12);
    }
    {
        Mat ps3 = mul(entry, P2);
        tw_local_store(ps3,         &tws[18], twb + 18);
    }

    // ---- final: full-chain product from quad lane 3 (DPP broadcast) ----
    Mat F;
    #pragma unroll
    for (int i = 0; i < 12; ++i) F.m[i] = qperm<QP_BCL3>(P.m[i]);

    float rr = init_rpy[0], pt = init_rpy[1], yw = init_rpy[2];
    float sr = __sinf(rr), cr = __cosf(rr);
    float sp = __sinf(pt), cp = __cosf(pt);
    float sy = __sinf(yw), cy = __cosf(yw);
    float i00 = cy*cp, i01 = cy*sp*sr - sy*cr, i02 = cy*sp*cr + sy*sr;
    float i10 = sy*cp, i11 = sy*sp*sr + cy*cr, i12 = sy*sp*cr - cy*sr;
    float i20 = -sp,   i21 = cp*sr,            i22 = cp*cr;
    float ip0 = init_p[0], ip1 = init_p[1], ip2 = init_p[2];

    float r0 = (s == 0) ? F.m[0] : (s == 1) ? F.m[3] : F.m[6];
    float r1 = (s == 0) ? F.m[1] : (s == 1) ? F.m[4] : F.m[7];
    float r2 = (s == 0) ? F.m[2] : (s == 1) ? F.m[5] : F.m[8];
    float pr = (s == 0) ? F.m[9] : (s == 1) ? F.m[10] : F.m[11];
    float4 row;
    row.x = r0*i00 + r1*i10 + r2*i20;
    row.y = r0*i01 + r1*i11 + r2*i21;
    row.z = r0*i02 + r1*i12 + r2*i22;
    row.w = r0*ip0 + r1*ip1 + r2*ip2 + pr;
    if (s == 3) row = make_float4(0.f, 0.f, 0.f, 1.f);

    reinterpret_cast<float4*>(outT)[(size_t)g] = row;
}

extern "C" void kernel_launch(void* const* d_in, const int* in_sizes, int n_in,
                              void* d_out, int out_size, void* d_ws, size_t ws_size,
                              hipStream_t stream) {
    const float* q        = (const float*)d_in[0];
    const float* twist    = (const float*)d_in[1];
    const float* init_p   = (const float*)d_in[2];
    const float* init_rpy = (const float*)d_in[3];

    int nb = in_sizes[0] / NJ;   // B
    float* outT  = (float*)d_out;                  // B x 16 (4x4 matrices)
    float* outTw = outT + (size_t)nb * 16;         // B x 96 (Twistls)

    int threads = nb * 4;                          // 4 lanes per element
    int blocks  = (threads + BLK - 1) / BLK;
    poe_fwd<<<blocks, BLK, 0, stream>>>(q, twist, init_p, init_rpy, outT, outTw, nb);
}

// Round 14
// 40.887 us; speedup vs baseline: 1.1737x; 1.1737x over previous
//
#include <hip/hip_runtime.h>
#include <math.h>

#define NJ    16
#define BLK   256
#define WAVES (BLK / 64)

// DPP quad_perm: cross-lane move WITHIN each 4-lane quad, executed on the
// VALU pipe (v_mov_b32_dpp) — zero DS ops, unlike __shfl (ds_bpermute).
template<int CTRL>
__device__ __forceinline__ float qperm(float x) {
    return __int_as_float(__builtin_amdgcn_update_dpp(
        __float_as_int(x), __float_as_int(x), CTRL, 0xF, 0xF, false));
}
#define QP_SHL1 144  // [0,0,1,2]: lane k <- k-1 (k>=1)
#define QP_SHL2 68   // [0,1,0,1]: lane k <- k-2 (k>=2)
#define QP_BCL3 255  // [3,3,3,3]: all lanes <- lane 3 of quad

// Affine 3x4: m[0..8] = row-major R, m[9..11] = p.
struct Mat { float m[12]; };

__device__ __forceinline__ Mat mul(const Mat& A, const Mat& B) {
    Mat C;
    #pragma unroll
    for (int r = 0; r < 3; ++r) {
        float a0 = A.m[3*r+0], a1 = A.m[3*r+1], a2 = A.m[3*r+2];
        C.m[3*r+0] = a0*B.m[0] + a1*B.m[3] + a2*B.m[6];
        C.m[3*r+1] = a0*B.m[1] + a1*B.m[4] + a2*B.m[7];
        C.m[3*r+2] = a0*B.m[2] + a1*B.m[5] + a2*B.m[8];
        C.m[9+r]   = a0*B.m[9] + a1*B.m[10] + a2*B.m[11] + A.m[9+r];
    }
    return C;
}

__device__ __forceinline__ Mat buildA(const float* tw6, float qj) {
    float w0 = tw6[0], w1 = tw6[1], w2 = tw6[2];
    float v0 = tw6[3], v1 = tw6[4], v2 = tw6[5];
    float theta = sqrtf(w0*w0 + w1*w1 + w2*w2) + 1e-12f;
    float inv   = __builtin_amdgcn_rcpf(theta);
    float wn0 = w0*inv, wn1 = w1*inv, wn2 = w2*inv;
    float vn0 = v0*inv, vn1 = v1*inv, vn2 = v2*inv;
    float qt  = qj * theta;
    float s   = __sinf(qt);
    float cth = __cosf(qt);
    float c   = 1.0f - cth;
    float ts  = qt - s;
    Mat A;
    A.m[0] = cth + c*wn0*wn0;   A.m[1] = c*wn0*wn1 - s*wn2; A.m[2] = c*wn0*wn2 + s*wn1;
    A.m[3] = c*wn1*wn0 + s*wn2; A.m[4] = cth + c*wn1*wn1;   A.m[5] = c*wn1*wn2 - s*wn0;
    A.m[6] = c*wn2*wn0 - s*wn1; A.m[7] = c*wn2*wn1 + s*wn0; A.m[8] = cth + c*wn2*wn2;
    float cx0 = wn1*vn2 - wn2*vn1;
    float cx1 = wn2*vn0 - wn0*vn2;
    float cx2 = wn0*vn1 - wn1*vn0;
    float d   = wn0*vn0 + wn1*vn1 + wn2*vn2;
    float td  = ts * d;
    A.m[9]  = s*vn0 + c*cx0 + td*wn0;
    A.m[10] = s*vn1 + c*cx1 + td*wn1;
    A.m[11] = s*vn2 + c*cx2 + td*wn2;
    return A;
}

// tw_local for one joint -> 6 floats into ob (static indices only).
__device__ __forceinline__ void tw_local(
    const Mat& pose, const float* t6, float* ob)
{
    float w0 = t6[0], w1 = t6[1], w2 = t6[2];
    float v0 = t6[3], v1 = t6[4], v2 = t6[5];
    float p0 = pose.m[9], p1 = pose.m[10], p2 = pose.m[11];
    float u0 = v0 - (p1*w2 - p2*w1);
    float u1 = v1 - (p2*w0 - p0*w2);
    float u2 = v2 - (p0*w1 - p1*w0);
    ob[0] = pose.m[0]*w0 + pose.m[3]*w1 + pose.m[6]*w2;
    ob[1] = pose.m[1]*w0 + pose.m[4]*w1 + pose.m[7]*w2;
    ob[2] = pose.m[2]*w0 + pose.m[5]*w1 + pose.m[8]*w2;
    ob[3] = pose.m[0]*u0 + pose.m[3]*u1 + pose.m[6]*u2;
    ob[4] = pose.m[1]*u0 + pose.m[4]*u1 + pose.m[7]*u2;
    ob[5] = pose.m[2]*u0 + pose.m[5]*u1 + pose.m[8]*u2;
}

// 4 lanes/element, DPP quad scan (R12 compute), wave-LDS-staged Twistls
// writeout: every global store instruction covers 16 fully-dense 64B lines.
__global__ __launch_bounds__(BLK) void poe_fwd(
    const float* __restrict__ q,        // B x 16
    const float* __restrict__ twist,    // 16 x 6 (uniform)
    const float* __restrict__ init_p,   // 3
    const float* __restrict__ init_rpy, // 3
    float* __restrict__ outT,           // B x 16
    float* __restrict__ outTw,          // B x 96
    int nb)
{
    // Per-wave staging: 64 rows x (6+1 pad) float4. Write banks: (7l+k)%8
    // uniform over lanes; reads near the 8-dword/bank structural floor.
    __shared__ float4 lds4[WAVES * 64 * 7];

    const int tid  = threadIdx.x;
    const int lane = tid & 63;
    const int wid  = tid >> 6;
    const int g    = blockIdx.x * BLK + tid;        // global lane
    const int e    = g >> 2;                        // batch element
    const int s    = g & 3;                         // segment (joints 4s..4s+3)
    if (e >= nb) return;

    float qk[4];
    {
        float4 t = reinterpret_cast<const float4*>(q)[(size_t)e * 4 + s];
        qk[0] = t.x; qk[1] = t.y; qk[2] = t.z; qk[3] = t.w;
    }

    // twist rows 4s..4s+3 (24 floats, L1-resident).
    float tws[24];
    {
        const float4* t4 = reinterpret_cast<const float4*>(twist) + s * 6;
        #pragma unroll
        for (int i = 0; i < 6; ++i) {
            float4 t = t4[i];
            tws[4*i+0] = t.x; tws[4*i+1] = t.y; tws[4*i+2] = t.z; tws[4*i+3] = t.w;
        }
    }

    // ---- phase 1: serial product of my segment ----
    Mat P = buildA(&tws[0], qk[0]);
    #pragma unroll
    for (int k = 1; k < 4; ++k)
        P = mul(P, buildA(&tws[6*k], qk[k]));

    // ---- inclusive scan over the quad via DPP (steps 1, 2) ----
    {
        Mat T;
        #pragma unroll
        for (int i = 0; i < 12; ++i) T.m[i] = qperm<QP_SHL1>(P.m[i]);
        Mat M = mul(T, P);
        #pragma unroll
        for (int i = 0; i < 12; ++i) P.m[i] = (s >= 1) ? M.m[i] : P.m[i];
    }
    {
        Mat T;
        #pragma unroll
        for (int i = 0; i < 12; ++i) T.m[i] = qperm<QP_SHL2>(P.m[i]);
        Mat M = mul(T, P);
        #pragma unroll
        for (int i = 0; i < 12; ++i) P.m[i] = (s >= 2) ? M.m[i] : P.m[i];
    }

    // ---- exclusive prefix = entry pose for my segment ----
    Mat pose;
    {
        #pragma unroll
        for (int i = 0; i < 12; ++i) pose.m[i] = qperm<QP_SHL1>(P.m[i]);
        const float id[12] = {1,0,0, 0,1,0, 0,0,1, 0,0,0};
        #pragma unroll
        for (int i = 0; i < 12; ++i) pose.m[i] = (s == 0) ? id[i] : pose.m[i];
    }

    // ---- phase 2: tw_local for my 4 joints into ob[24] (registers) ----
    float ob[24];
    #pragma unroll
    for (int k = 0; k < 4; ++k) {
        tw_local(pose, &tws[6*k], &ob[6*k]);
        if (k < 3)
            pose = mul(pose, buildA(&tws[6*k], qk[k]));
    }

    // ---- staged writeout: LDS row (pad 7), then 6 dense float4 bursts ----
    {
        float4* wbuf = &lds4[wid * (64 * 7)];
        float4* wrow = &wbuf[lane * 7];
        #pragma unroll
        for (int c = 0; c < 6; ++c)
            wrow[c] = make_float4(ob[4*c+0], ob[4*c+1], ob[4*c+2], ob[4*c+3]);
        // wave's 16 elements span 6144 B contiguous in outTw
        const int wf = blockIdx.x * BLK + wid * 64;      // wave's first g
        float4* dst = reinterpret_cast<float4*>(outTw) + (size_t)wf * 6;
        #pragma unroll
        for (int i = 0; i < 6; ++i) {
            int g4 = i * 64 + lane;      // wave-linear float4 index, 0..383
            int r  = g4 / 6;             // source thread (row)
            int c  = g4 - r * 6;         // float4 within row
            dst[g4] = wbuf[r * 7 + c];
        }
    }

    // ---- final: full-chain product from quad lane 3 (DPP broadcast) ----
    Mat F;
    #pragma unroll
    for (int i = 0; i < 12; ++i) F.m[i] = qperm<QP_BCL3>(P.m[i]);

    float rr = init_rpy[0], pt = init_rpy[1], yw = init_rpy[2];
    float sr = __sinf(rr), cr = __cosf(rr);
    float sp = __sinf(pt), cp = __cosf(pt);
    float sy = __sinf(yw), cy = __cosf(yw);
    float i00 = cy*cp, i01 = cy*sp*sr - sy*cr, i02 = cy*sp*cr + sy*sr;
    float i10 = sy*cp, i11 = sy*sp*sr + cy*cr, i12 = sy*sp*cr - cy*sr;
    float i20 = -sp,   i21 = cp*sr,            i22 = cp*cr;
    float ip0 = init_p[0], ip1 = init_p[1], ip2 = init_p[2];

    float r0 = (s == 0) ? F.m[0] : (s == 1) ? F.m[3] : F.m[6];
    float r1 = (s == 0) ? F.m[1] : (s == 1) ? F.m[4] : F.m[7];
    float r2 = (s == 0) ? F.m[2] : (s == 1) ? F.m[5] : F.m[8];
    float pr = (s == 0) ? F.m[9] : (s == 1) ? F.m[10] : F.m[11];
    float4 row;
    row.x = r0*i00 + r1*i10 + r2*i20;
    row.y = r0*i01 + r1*i11 + r2*i21;
    row.z = r0*i02 + r1*i12 + r2*i22;
    row.w = r0*ip0 + r1*ip1 + r2*ip2 + pr;
    if (s == 3) row = make_float4(0.f, 0.f, 0.f, 1.f);

    reinterpret_cast<float4*>(outT)[(size_t)g] = row;   // already dense/inst
}

extern "C" void kernel_launch(void* const* d_in, const int* in_sizes, int n_in,
                              void* d_out, int out_size, void* d_ws, size_t ws_size,
                              hipStream_t stream) {
    const float* q        = (const float*)d_in[0];
    const float* twist    = (const float*)d_in[1];
    const float* init_p   = (const float*)d_in[2];
    const float* init_rpy = (const float*)d_in[3];

    int nb = in_sizes[0] / NJ;   // B (divisible by 64 per wave-staging)
    float* outT  = (float*)d_out;                  // B x 16 (4x4 matrices)
    float* outTw = outT + (size_t)nb * 16;         // B x 96 (Twistls)

    int threads = nb * 4;                          // 4 lanes per element
    int blocks  = (threads + BLK - 1) / BLK;
    poe_fwd<<<blocks, BLK, 0, stream>>>(q, twist, init_p, init_rpy, outT, outTw, nb);
}